// Round 5
// baseline (236.559 us; speedup 1.0000x reference)
//
#include <hip/hip_runtime.h>
#include <cstdint>
#include <cstddef>

#define DEVI __device__ __forceinline__

typedef short    shortx8 __attribute__((ext_vector_type(8)));
typedef short    shortx4 __attribute__((ext_vector_type(4)));
typedef short    shortx2 __attribute__((ext_vector_type(2)));
typedef __bf16   bf16x8  __attribute__((ext_vector_type(8)));
typedef float    floatx4 __attribute__((ext_vector_type(4)));

DEVI unsigned short f2b(float f) {
    union { float f; unsigned u; } a; a.f = f;
    unsigned r = a.u + 0x7fffu + ((a.u >> 16) & 1u);
    return (unsigned short)(r >> 16);
}
DEVI float b2f(unsigned short u) {
    union { unsigned u; float f; } a; a.u = ((unsigned)u) << 16;
    return a.f;
}

DEVI floatx4 mfma_bf16(bf16x8 a, bf16x8 b, floatx4 c) {
    return __builtin_amdgcn_mfma_f32_16x16x32_bf16(a, b, c, 0, 0, 0);
}

DEVI void glds16(const ushort* g, ushort* l) {
    __builtin_amdgcn_global_load_lds(
        (const __attribute__((address_space(1))) void*)g,
        (__attribute__((address_space(3))) void*)l, 16, 0, 0);
}

// ------------- fused prep: x->bf16, W transposes, bias pack, kv zero ----------
__global__ void k_prep(const float* __restrict__ x, ushort* __restrict__ xb,
                       const float* __restrict__ Wq, const float* __restrict__ Wk,
                       const float* __restrict__ Wv, const float* __restrict__ Wo,
                       ushort* __restrict__ Wt, ushort* __restrict__ Wot,
                       const float* __restrict__ bq, const float* __restrict__ bk,
                       const float* __restrict__ bv, float* __restrict__ bqkv,
                       float* __restrict__ kvp) {
    __shared__ float tile[64][65];
    const int bid = blockIdx.x, t = threadIdx.x;
    if (bid < 6144) {                      // x -> bf16
        size_t i = ((size_t)bid * 256 + t) * 8;
        float4 v0 = *(const float4*)(x + i);
        float4 v1 = *(const float4*)(x + i + 4);
        shortx8 o;
        o[0] = (short)f2b(v0.x); o[1] = (short)f2b(v0.y);
        o[2] = (short)f2b(v0.z); o[3] = (short)f2b(v0.w);
        o[4] = (short)f2b(v1.x); o[5] = (short)f2b(v1.y);
        o[6] = (short)f2b(v1.z); o[7] = (short)f2b(v1.w);
        *(shortx8*)(xb + i) = o;
    } else if (bid < 6720) {               // W [in][out] fp32 -> [out][in] bf16
        int pid = bid - 6144;
        int zi = pid / 144, rem = pid % 144;
        const float* W = (zi == 0) ? Wq : (zi == 1) ? Wk : (zi == 2) ? Wv : Wo;
        const int i0 = (rem / 12) * 64, j0 = (rem % 12) * 64;
        const int c = t & 63, r4 = t >> 6;
        for (int rr = r4; rr < 64; rr += 4)
            tile[rr][c] = W[(size_t)(i0 + rr) * 768 + j0 + c];
        __syncthreads();
        ushort* dst = (zi < 3) ? (Wt + (size_t)(zi * 768) * 768) : Wot;
        for (int jj = r4; jj < 64; jj += 4)
            dst[(size_t)(j0 + jj) * 768 + i0 + c] = f2b(tile[c][jj]);
    } else if (bid < 6729) {               // bias pack
        int j = (bid - 6720) * 256 + t;
        if (j < 2304) {
            const float* src = (j < 768) ? bq : (j < 1536) ? bk : bv;
            bqkv[j] = src[j % 768];
        }
    } else {                               // zero kv accumulator (48*65*64 f32)
        int idx = (bid - 6729) * 1024 + t * 4;   // 195 blocks * 1024 == 199680
        float4 z = {0.f, 0.f, 0.f, 0.f};
        *(float4*)(kvp + idx) = z;
    }
}

// ---------------- main GEMM: BK=64, XOR chunk swizzle + locality swizzle ------
// (FROZEN since round 4 — at the m97-structure ceiling for this shape.)
// LDS logical As[row][k0..63]; element (r,k) at r*64 + ((k>>3)^(r&7))*8 + (k&7).
// Staging: glds16 #i covers rows +i*8..+i*8+8, lane -> (row=lane>>3, slot=lane&7),
// source column permuted per lane so coalescing (full 128B rows) is preserved.
// Block-index swizzle: XCD chunking (m204) + 8-m-block band traversal.
template <int MODE>
__global__ __launch_bounds__(256, 4) void k_gemm(
    const ushort* __restrict__ A, const ushort* __restrict__ Bt,
    const float* __restrict__ bias, void* __restrict__ Cout, int Ncols) {
    constexpr int K = 768;
    constexpr int GY = (MODE == 0) ? 18 : 6;   // grid.y (must match launch)
    constexpr int NWG = 128 * GY;
    __shared__ ushort As[128 * 64];
    __shared__ ushort Bs[128 * 64];

    const int lin  = blockIdx.y * 128 + blockIdx.x;       // dispatch order
    const int wg   = (lin & 7) * (NWG / 8) + (lin >> 3);  // XCD-contiguous
    const int band = wg / (8 * GY);                       // super-row of 8 m-blocks
    const int rem  = wg % (8 * GY);
    const int m0 = (band * 8 + (rem & 7)) * 128;
    const int n0 = (rem >> 3) * 128;

    const int tid = threadIdx.x;
    const int w = tid >> 6, lane = tid & 63;

    const int lr = lane >> 3;                    // row within 8-row slab
    const int lc = ((lane & 7) ^ lr) * 8;        // swizzled source chunk
    const ushort* aBase = A  + (size_t)(m0 + w * 32 + lr) * K + lc;
    const ushort* bBase = Bt + (size_t)(n0 + w * 32 + lr) * K + lc;
    ushort* aL = As + (w * 32) * 64;             // wave-uniform LDS bases
    ushort* bL = Bs + (w * 32) * 64;

    const int rBase = (w >> 1) * 64;
    const int nBase = (w & 1) * 64;
    const int fr = lane & 15;
    const int q4 = lane >> 4;

    floatx4 acc[4][4] = {};

    for (int k0 = 0; k0 < K; k0 += 64) {
#pragma unroll
        for (int i = 0; i < 4; ++i) glds16(aBase + i * (8 * K) + k0, aL + i * (8 * 64));
#pragma unroll
        for (int i = 0; i < 4; ++i) glds16(bBase + i * (8 * K) + k0, bL + i * (8 * 64));
        __syncthreads();
#pragma unroll
        for (int kc = 0; kc < 2; ++kc) {
            const int off = ((kc * 4 + q4) ^ (fr & 7)) * 8;
            bf16x8 af[4], bf[4];
#pragma unroll
            for (int rt = 0; rt < 4; ++rt)
                af[rt] = *(const bf16x8*)(As + (rBase + rt * 16 + fr) * 64 + off);
#pragma unroll
            for (int nt = 0; nt < 4; ++nt)
                bf[nt] = *(const bf16x8*)(Bs + (nBase + nt * 16 + fr) * 64 + off);
#pragma unroll
            for (int rt = 0; rt < 4; ++rt)
#pragma unroll
                for (int nt = 0; nt < 4; ++nt)
                    acc[rt][nt] = mfma_bf16(af[rt], bf[nt], acc[rt][nt]);
        }
        __syncthreads();
    }

#pragma unroll
    for (int rt = 0; rt < 4; ++rt) {
#pragma unroll
        for (int nt = 0; nt < 4; ++nt) {
#pragma unroll
            for (int r = 0; r < 4; ++r) {
                int m = m0 + rBase + rt * 16 + q4 * 4 + r;
                int n = n0 + nBase + nt * 16 + fr;
                float v = acc[rt][nt][r] + bias[n];
                if (MODE == 0) {
                    if (n < 1536) v = (v > 0.f) ? (v + 1.f) : __expf(v);  // phi
                    ((ushort*)Cout)[(size_t)m * Ncols + n] = f2b(v);
                } else {
                    ((float*)Cout)[(size_t)m * Ncols + n] = v;
                }
            }
        }
    }
}

// ---------------- kv + ksum via MFMA: 256 rows/block, dbuf + early-issue ------
// Round-5 rebuild: grid (48,16) -> 768 blocks = 3/CU, fully resident in one
// round. Per block 4 slabs of 64 rows; LDS double-buffered (2 x (kS+vS), 35 KB)
// with T14 early-issue: slab rr+1's global loads issue right after the barrier
// (before slab rr's MFMA), regs -> LDS after the MFMA. One barrier per slab;
// all waits compiler-inserted (no inline asm). Results accumulated into a
// single f32 kv buffer via atomicAdd (zeroed by k_prep) -> k_kvred eliminated.
#define KV_LOAD(rr, r)  do {                                          \
    const ushort* kp = base + (size_t)((rr) * 64 + n_ld) * 2304;      \
    r[0] = *(const shortx8*)(kp);                                     \
    r[1] = *(const shortx8*)(kp + 8);                                 \
    r[2] = *(const shortx8*)(kp + 768);                               \
    r[3] = *(const shortx8*)(kp + 776); } while (0)

#define KV_STORE(buf, r) do {                                         \
    union { shortx8 v8; shortx2 v2[4]; } u0, u1, u2, u3;              \
    u0.v8 = r[0]; u1.v8 = r[1]; u2.v8 = r[2]; u3.v8 = r[3];           \
    ushort* kd = kS[buf] + n_ld * 70 + c16;                           \
    ushort* vd = vS[buf] + n_ld * 70 + c16;                           \
    _Pragma("unroll")                                                 \
    for (int i = 0; i < 4; ++i) {                                     \
        *(shortx2*)(kd + 2 * i)     = u0.v2[i];                       \
        *(shortx2*)(kd + 8 + 2 * i) = u1.v2[i];                       \
        *(shortx2*)(vd + 2 * i)     = u2.v2[i];                       \
        *(shortx2*)(vd + 8 + 2 * i) = u3.v2[i]; } } while (0)

__global__ __launch_bounds__(256) void k_kv(const ushort* __restrict__ QKV,
                                            float* __restrict__ kvp) {
    const int bh = blockIdx.x, s = blockIdx.y;           // s in [0,16)
    const int bb = bh / 12, head = bh % 12;
    __shared__ ushort kS[2][64 * 70];
    __shared__ ushort vS[2][64 * 70];
    const int t = threadIdx.x, w = t >> 6, lane = t & 63;
    const int fr = lane & 15, fk = (lane >> 4) * 8;

    floatx4 acc[5] = {};
    const int n_ld = t >> 2, c16 = (t & 3) * 16;
    const ushort* base = QKV + (size_t)(bb * 4096 + s * 256) * 2304 + 768 + head * 64 + c16;

    union { bf16x8 v; ushort u[8]; } ones;
    {
        ushort ov = (fr == 0) ? (ushort)0x3F80 : (ushort)0;
#pragma unroll
        for (int i = 0; i < 8; ++i) ones.u[i] = ov;
    }

    shortx8 rA[4], rB[4];
    KV_LOAD(0, rA);
    KV_STORE(0, rA);

#pragma unroll
    for (int rr = 0; rr < 4; ++rr) {
        __syncthreads();                   // prior ds_writes visible; prior reads done
        if (rr == 0)      KV_LOAD(1, rB);  // early-issue: latency hides under MFMA
        else if (rr == 1) KV_LOAD(2, rA);
        else if (rr == 2) KV_LOAD(3, rB);
        const int buf = rr & 1;
#pragma unroll
        for (int kl = 0; kl < 64; kl += 32) {
            union { bf16x8 v; ushort u[8]; } bfr, afr[4];
#pragma unroll
            for (int i = 0; i < 8; ++i) {
                int n = kl + fk + i;
                bfr.u[i] = kS[buf][n * 70 + w * 16 + fr];
#pragma unroll
                for (int mt = 0; mt < 4; ++mt)
                    afr[mt].u[i] = vS[buf][n * 70 + mt * 16 + fr];
            }
#pragma unroll
            for (int mt = 0; mt < 4; ++mt)
                acc[mt] = mfma_bf16(afr[mt].v, bfr.v, acc[mt]);
            acc[4] = mfma_bf16(ones.v, bfr.v, acc[4]);
        }
        if (rr == 0)      KV_STORE(1, rB); // write other buffer (readers done at rr-1)
        else if (rr == 1) KV_STORE(0, rA);
        else if (rr == 2) KV_STORE(1, rB);
    }

    float* dst = kvp + (size_t)bh * (65 * 64);
#pragma unroll
    for (int mt = 0; mt < 4; ++mt)
#pragma unroll
        for (int r = 0; r < 4; ++r)
            atomicAdd(dst + (mt * 16 + (lane >> 4) * 4 + r) * 64 + w * 16 + fr,
                      acc[mt][r]);
    if (lane < 16) atomicAdd(dst + 64 * 64 + w * 16 + lane, acc[4][0]);
}

// ---------------- num + z + normed (MFMA); kvT staged from f32 kv -------------
__global__ __launch_bounds__(256) void k_num(const ushort* __restrict__ QKV,
                                             const float* __restrict__ kvp,
                                             ushort* __restrict__ normed) {
    const int bh = blockIdx.x, l0 = blockIdx.y * 128;
    const int bb = bh / 12, head = bh % 12;
    __shared__ ushort qsh[128 * 72];
    __shared__ ushort kvT[80 * 72];
    __shared__ float dnm[128];
    const int t = threadIdx.x, w = t >> 6, lane = t & 63;

    {
        const float* kvf = kvp + (size_t)bh * 4160;
        int c4 = (t & 15) * 4;                 // 16 thr x 4 f32 = one 64-col row
        for (int r0 = (t >> 4); r0 < 65; r0 += 16) {
            float4 a = *(const float4*)(kvf + r0 * 64 + c4);
            shortx4 o;
            o[0] = (short)f2b(a.x); o[1] = (short)f2b(a.y);
            o[2] = (short)f2b(a.z); o[3] = (short)f2b(a.w);
            *(shortx4*)(kvT + r0 * 72 + c4) = o;
        }
    }
    for (int idx = t; idx < 15 * 72; idx += 256) kvT[65 * 72 + idx] = 0;

    const ushort* qg = QKV + (size_t)(bb * 4096 + l0) * 2304 + head * 64;
    {
        int row = t >> 3, c8 = (t & 7) * 8;
#pragma unroll
        for (int i = 0; i < 4; ++i) {
            shortx8 v = *(const shortx8*)(qg + (size_t)(i * 32 + row) * 2304 + c8);
            *(shortx8*)(qsh + (i * 32 + row) * 72 + c8) = v;
        }
    }
    __syncthreads();

    const int fr = lane & 15, fk = (lane >> 4) * 8;
    floatx4 acc[2][5] = {};
#pragma unroll
    for (int kc = 0; kc < 2; ++kc) {
        bf16x8 a[2], b[5];
#pragma unroll
        for (int rt = 0; rt < 2; ++rt)
            a[rt] = *(const bf16x8*)(qsh + (w * 32 + rt * 16 + fr) * 72 + kc * 32 + fk);
#pragma unroll
        for (int nt = 0; nt < 5; ++nt)
            b[nt] = *(const bf16x8*)(kvT + (nt * 16 + fr) * 72 + kc * 32 + fk);
#pragma unroll
        for (int rt = 0; rt < 2; ++rt)
#pragma unroll
            for (int nt = 0; nt < 5; ++nt)
                acc[rt][nt] = mfma_bf16(a[rt], b[nt], acc[rt][nt]);
    }
    if (fr == 0) {
#pragma unroll
        for (int rt = 0; rt < 2; ++rt)
#pragma unroll
            for (int r = 0; r < 4; ++r)
                dnm[w * 32 + rt * 16 + (lane >> 4) * 4 + r] = acc[rt][4][r];
    }
    __syncthreads();
#pragma unroll
    for (int rt = 0; rt < 2; ++rt) {
#pragma unroll
        for (int r = 0; r < 4; ++r) {
            int ml = w * 32 + rt * 16 + (lane >> 4) * 4 + r;
            float z = 1.f / dnm[ml];
            size_t base = (size_t)(bb * 4096 + l0 + ml) * 768 + head * 64;
#pragma unroll
            for (int nt = 0; nt < 4; ++nt)
                normed[base + nt * 16 + fr] = f2b(acc[rt][nt][r] * z);
        }
    }
}

// ---------------- launch ----------------
extern "C" void kernel_launch(void* const* d_in, const int* in_sizes, int n_in,
                              void* d_out, int out_size, void* d_ws, size_t ws_size,
                              hipStream_t stream) {
    const float* x  = (const float*)d_in[0];
    const float* Wq = (const float*)d_in[1];
    const float* bq = (const float*)d_in[2];
    const float* Wk = (const float*)d_in[3];
    const float* bk = (const float*)d_in[4];
    const float* Wv = (const float*)d_in[5];
    const float* bv = (const float*)d_in[6];
    const float* Wo = (const float*)d_in[7];
    const float* bo = (const float*)d_in[8];

    char* ws = (char*)d_ws;
    ushort* Xb   = (ushort*)(ws);                 // 25,165,824 B (reused as normed)
    ushort* Wt   = (ushort*)(ws + 25165824);      //  3,538,944 B
    ushort* Wot  = (ushort*)(ws + 28704768);      //  1,179,648 B
    float*  bqkv = (float*)(ws + 29884416);       //      9,216 B
    ushort* QKV  = (ushort*)(ws + 29893632);      // 75,497,472 B
    float*  kvp  = (float*)(ws + 105391104);      //    798,720 B (f32 kv, atomic)
    ushort* normed = Xb;

    k_prep <<<dim3(6924),      256, 0, stream>>>(x, Xb, Wq, Wk, Wv, Wo, Wt, Wot,
                                                 bq, bk, bv, bqkv, kvp);
    k_gemm<0><<<dim3(128, 18), 256, 0, stream>>>(Xb, Wt, bqkv, (void*)QKV, 2304);
    k_kv   <<<dim3(48, 16),    256, 0, stream>>>(QKV, kvp);
    k_num  <<<dim3(48, 32),    256, 0, stream>>>(QKV, kvp, normed);
    k_gemm<1><<<dim3(128, 6),  256, 0, stream>>>(normed, Wot, bo, d_out, 768);
}

// Round 6
// 230.899 us; speedup vs baseline: 1.0245x; 1.0245x over previous
//
#include <hip/hip_runtime.h>
#include <cstdint>
#include <cstddef>

#define DEVI __device__ __forceinline__

typedef short    shortx8 __attribute__((ext_vector_type(8)));
typedef short    shortx4 __attribute__((ext_vector_type(4)));
typedef short    shortx2 __attribute__((ext_vector_type(2)));
typedef __bf16   bf16x8  __attribute__((ext_vector_type(8)));
typedef float    floatx4 __attribute__((ext_vector_type(4)));

DEVI unsigned short f2b(float f) {
    union { float f; unsigned u; } a; a.f = f;
    unsigned r = a.u + 0x7fffu + ((a.u >> 16) & 1u);
    return (unsigned short)(r >> 16);
}
DEVI float b2f(unsigned short u) {
    union { unsigned u; float f; } a; a.u = ((unsigned)u) << 16;
    return a.f;
}

DEVI floatx4 mfma_bf16(bf16x8 a, bf16x8 b, floatx4 c) {
    return __builtin_amdgcn_mfma_f32_16x16x32_bf16(a, b, c, 0, 0, 0);
}

DEVI void glds16(const ushort* g, ushort* l) {
    __builtin_amdgcn_global_load_lds(
        (const __attribute__((address_space(1))) void*)g,
        (__attribute__((address_space(3))) void*)l, 16, 0, 0);
}

// ---------------- fused prep: x->bf16, W transposes, bias pack ----------------
__global__ void k_prep(const float* __restrict__ x, ushort* __restrict__ xb,
                       const float* __restrict__ Wq, const float* __restrict__ Wk,
                       const float* __restrict__ Wv, const float* __restrict__ Wo,
                       ushort* __restrict__ Wt, ushort* __restrict__ Wot,
                       const float* __restrict__ bq, const float* __restrict__ bk,
                       const float* __restrict__ bv, float* __restrict__ bqkv) {
    __shared__ float tile[64][65];
    const int bid = blockIdx.x, t = threadIdx.x;
    if (bid < 6144) {                      // x -> bf16
        size_t i = ((size_t)bid * 256 + t) * 8;
        float4 v0 = *(const float4*)(x + i);
        float4 v1 = *(const float4*)(x + i + 4);
        shortx8 o;
        o[0] = (short)f2b(v0.x); o[1] = (short)f2b(v0.y);
        o[2] = (short)f2b(v0.z); o[3] = (short)f2b(v0.w);
        o[4] = (short)f2b(v1.x); o[5] = (short)f2b(v1.y);
        o[6] = (short)f2b(v1.z); o[7] = (short)f2b(v1.w);
        *(shortx8*)(xb + i) = o;
    } else if (bid < 6720) {               // W [in][out] fp32 -> [out][in] bf16
        int pid = bid - 6144;
        int zi = pid / 144, rem = pid % 144;
        const float* W = (zi == 0) ? Wq : (zi == 1) ? Wk : (zi == 2) ? Wv : Wo;
        const int i0 = (rem / 12) * 64, j0 = (rem % 12) * 64;
        const int c = t & 63, r4 = t >> 6;
        for (int rr = r4; rr < 64; rr += 4)
            tile[rr][c] = W[(size_t)(i0 + rr) * 768 + j0 + c];
        __syncthreads();
        ushort* dst = (zi < 3) ? (Wt + (size_t)(zi * 768) * 768) : Wot;
        for (int jj = r4; jj < 64; jj += 4)
            dst[(size_t)(j0 + jj) * 768 + i0 + c] = f2b(tile[c][jj]);
    } else {                               // bias pack
        int j = (bid - 6720) * 256 + t;
        if (j < 2304) {
            const float* src = (j < 768) ? bq : (j < 1536) ? bk : bv;
            bqkv[j] = src[j % 768];
        }
    }
}

// ---------------- main GEMM: BK=64, XOR chunk swizzle + locality swizzle ------
// (FROZEN since round 4 — at the m97-structure ceiling for this shape.)
// LDS logical As[row][k0..63]; element (r,k) at r*64 + ((k>>3)^(r&7))*8 + (k&7).
// Staging: glds16 #i covers rows +i*8..+i*8+8, lane -> (row=lane>>3, slot=lane&7),
// source column permuted per lane so coalescing (full 128B rows) is preserved.
// Block-index swizzle: XCD chunking (m204) + 8-m-block band traversal.
template <int MODE>
__global__ __launch_bounds__(256, 4) void k_gemm(
    const ushort* __restrict__ A, const ushort* __restrict__ Bt,
    const float* __restrict__ bias, void* __restrict__ Cout, int Ncols) {
    constexpr int K = 768;
    constexpr int GY = (MODE == 0) ? 18 : 6;   // grid.y (must match launch)
    constexpr int NWG = 128 * GY;
    __shared__ ushort As[128 * 64];
    __shared__ ushort Bs[128 * 64];

    const int lin  = blockIdx.y * 128 + blockIdx.x;       // dispatch order
    const int wg   = (lin & 7) * (NWG / 8) + (lin >> 3);  // XCD-contiguous
    const int band = wg / (8 * GY);                       // super-row of 8 m-blocks
    const int rem  = wg % (8 * GY);
    const int m0 = (band * 8 + (rem & 7)) * 128;
    const int n0 = (rem >> 3) * 128;

    const int tid = threadIdx.x;
    const int w = tid >> 6, lane = tid & 63;

    const int lr = lane >> 3;                    // row within 8-row slab
    const int lc = ((lane & 7) ^ lr) * 8;        // swizzled source chunk
    const ushort* aBase = A  + (size_t)(m0 + w * 32 + lr) * K + lc;
    const ushort* bBase = Bt + (size_t)(n0 + w * 32 + lr) * K + lc;
    ushort* aL = As + (w * 32) * 64;             // wave-uniform LDS bases
    ushort* bL = Bs + (w * 32) * 64;

    const int rBase = (w >> 1) * 64;
    const int nBase = (w & 1) * 64;
    const int fr = lane & 15;
    const int q4 = lane >> 4;

    floatx4 acc[4][4] = {};

    for (int k0 = 0; k0 < K; k0 += 64) {
#pragma unroll
        for (int i = 0; i < 4; ++i) glds16(aBase + i * (8 * K) + k0, aL + i * (8 * 64));
#pragma unroll
        for (int i = 0; i < 4; ++i) glds16(bBase + i * (8 * K) + k0, bL + i * (8 * 64));
        __syncthreads();
#pragma unroll
        for (int kc = 0; kc < 2; ++kc) {
            const int off = ((kc * 4 + q4) ^ (fr & 7)) * 8;
            bf16x8 af[4], bf[4];
#pragma unroll
            for (int rt = 0; rt < 4; ++rt)
                af[rt] = *(const bf16x8*)(As + (rBase + rt * 16 + fr) * 64 + off);
#pragma unroll
            for (int nt = 0; nt < 4; ++nt)
                bf[nt] = *(const bf16x8*)(Bs + (nBase + nt * 16 + fr) * 64 + off);
#pragma unroll
            for (int rt = 0; rt < 4; ++rt)
#pragma unroll
                for (int nt = 0; nt < 4; ++nt)
                    acc[rt][nt] = mfma_bf16(af[rt], bf[nt], acc[rt][nt]);
        }
        __syncthreads();
    }

#pragma unroll
    for (int rt = 0; rt < 4; ++rt) {
#pragma unroll
        for (int nt = 0; nt < 4; ++nt) {
#pragma unroll
            for (int r = 0; r < 4; ++r) {
                int m = m0 + rBase + rt * 16 + q4 * 4 + r;
                int n = n0 + nBase + nt * 16 + fr;
                float v = acc[rt][nt][r] + bias[n];
                if (MODE == 0) {
                    if (n < 1536) v = (v > 0.f) ? (v + 1.f) : __expf(v);  // phi
                    ((ushort*)Cout)[(size_t)m * Ncols + n] = f2b(v);
                } else {
                    ((float*)Cout)[(size_t)m * Ncols + n] = v;
                }
            }
        }
    }
}

// ---------------- kv + ksum via MFMA: 256 rows/block, dbuf + early-issue ------
// Round-6: keep round-5's balanced grid (48,16) -> 768 blocks = 3/CU, one
// resident round, and the LDS double-buffer + T14 early-issue (slab rr+1's
// global loads issue before slab rr's MFMA; regs -> LDS after). DROP the
// atomicAdd finale (round-5 regression suspect): plain f32 partial stores
// indexed by s, folded by k_kvred (16 partials). No inline asm; all waits
// compiler-inserted.
#define KV_LOAD(rr, r)  do {                                          \
    const ushort* kp = base + (size_t)((rr) * 64 + n_ld) * 2304;      \
    r[0] = *(const shortx8*)(kp);                                     \
    r[1] = *(const shortx8*)(kp + 8);                                 \
    r[2] = *(const shortx8*)(kp + 768);                               \
    r[3] = *(const shortx8*)(kp + 776); } while (0)

#define KV_STORE(buf, r) do {                                         \
    union { shortx8 v8; shortx2 v2[4]; } u0, u1, u2, u3;              \
    u0.v8 = r[0]; u1.v8 = r[1]; u2.v8 = r[2]; u3.v8 = r[3];           \
    ushort* kd = kS[buf] + n_ld * 70 + c16;                           \
    ushort* vd = vS[buf] + n_ld * 70 + c16;                           \
    _Pragma("unroll")                                                 \
    for (int i = 0; i < 4; ++i) {                                     \
        *(shortx2*)(kd + 2 * i)     = u0.v2[i];                       \
        *(shortx2*)(kd + 8 + 2 * i) = u1.v2[i];                       \
        *(shortx2*)(vd + 2 * i)     = u2.v2[i];                       \
        *(shortx2*)(vd + 8 + 2 * i) = u3.v2[i]; } } while (0)

__global__ __launch_bounds__(256) void k_kv(const ushort* __restrict__ QKV,
                                            float* __restrict__ kvp) {
    const int bh = blockIdx.x, s = blockIdx.y;           // s in [0,16)
    const int bb = bh / 12, head = bh % 12;
    __shared__ ushort kS[2][64 * 70];
    __shared__ ushort vS[2][64 * 70];
    const int t = threadIdx.x, w = t >> 6, lane = t & 63;
    const int fr = lane & 15, fk = (lane >> 4) * 8;

    floatx4 acc[5] = {};
    const int n_ld = t >> 2, c16 = (t & 3) * 16;
    const ushort* base = QKV + (size_t)(bb * 4096 + s * 256) * 2304 + 768 + head * 64 + c16;

    union { bf16x8 v; ushort u[8]; } ones;
    {
        ushort ov = (fr == 0) ? (ushort)0x3F80 : (ushort)0;
#pragma unroll
        for (int i = 0; i < 8; ++i) ones.u[i] = ov;
    }

    shortx8 rA[4], rB[4];
    KV_LOAD(0, rA);
    KV_STORE(0, rA);

#pragma unroll
    for (int rr = 0; rr < 4; ++rr) {
        __syncthreads();                   // prior ds_writes visible; prior reads done
        if (rr == 0)      KV_LOAD(1, rB);  // early-issue: latency hides under MFMA
        else if (rr == 1) KV_LOAD(2, rA);
        else if (rr == 2) KV_LOAD(3, rB);
        const int buf = rr & 1;
#pragma unroll
        for (int kl = 0; kl < 64; kl += 32) {
            union { bf16x8 v; ushort u[8]; } bfr, afr[4];
#pragma unroll
            for (int i = 0; i < 8; ++i) {
                int n = kl + fk + i;
                bfr.u[i] = kS[buf][n * 70 + w * 16 + fr];
#pragma unroll
                for (int mt = 0; mt < 4; ++mt)
                    afr[mt].u[i] = vS[buf][n * 70 + mt * 16 + fr];
            }
#pragma unroll
            for (int mt = 0; mt < 4; ++mt)
                acc[mt] = mfma_bf16(afr[mt].v, bfr.v, acc[mt]);
            acc[4] = mfma_bf16(ones.v, bfr.v, acc[4]);
        }
        if (rr == 0)      KV_STORE(1, rB); // write other buffer (readers done at rr-1)
        else if (rr == 1) KV_STORE(0, rA);
        else if (rr == 2) KV_STORE(1, rB);
    }

    float* dst = kvp + ((size_t)bh * 16 + s) * (65 * 64);
#pragma unroll
    for (int mt = 0; mt < 4; ++mt)
#pragma unroll
        for (int r = 0; r < 4; ++r)
            dst[(mt * 16 + (lane >> 4) * 4 + r) * 64 + w * 16 + fr] = acc[mt][r];
    if (lane < 16) dst[64 * 64 + w * 16 + lane] = acc[4][0];
}

// reduce 16 partials, emit bf16: kvb [48][65][64]
__global__ void k_kvred(const float* __restrict__ kvp, ushort* __restrict__ kvb) {
    int t4 = (blockIdx.x * 256 + threadIdx.x) * 4;   // 195*256*4 == 199680
    int bh = t4 / 4160, rem = t4 % 4160;
    const float* p = kvp + (size_t)bh * 16 * 4160 + rem;
    float4 sum = {0.f, 0.f, 0.f, 0.f};
    for (int i = 0; i < 16; ++i) {
        float4 a = *(const float4*)(p + (size_t)i * 4160);
        sum.x += a.x; sum.y += a.y; sum.z += a.z; sum.w += a.w;
    }
    shortx4 o;
    o[0] = (short)f2b(sum.x); o[1] = (short)f2b(sum.y);
    o[2] = (short)f2b(sum.z); o[3] = (short)f2b(sum.w);
    *(shortx4*)(kvb + t4) = o;
}

// ---------------- num + z + normed (MFMA) ----------------
__global__ __launch_bounds__(256) void k_num(const ushort* __restrict__ QKV,
                                             const ushort* __restrict__ kvb,
                                             ushort* __restrict__ normed) {
    const int bh = blockIdx.x, l0 = blockIdx.y * 128;
    const int bb = bh / 12, head = bh % 12;
    __shared__ ushort qsh[128 * 72];
    __shared__ ushort kvT[80 * 72];
    __shared__ float dnm[128];
    const int t = threadIdx.x, w = t >> 6, lane = t & 63;

    {
        const ushort* kvbb = kvb + (size_t)bh * 4160;
        int c8 = (t & 7) * 8;
        for (int r0 = (t >> 3); r0 < 65; r0 += 32)
            *(shortx8*)(kvT + r0 * 72 + c8) = *(const shortx8*)(kvbb + r0 * 64 + c8);
    }
    for (int idx = t; idx < 15 * 72; idx += 256) kvT[65 * 72 + idx] = 0;

    const ushort* qg = QKV + (size_t)(bb * 4096 + l0) * 2304 + head * 64;
    {
        int row = t >> 3, c8 = (t & 7) * 8;
#pragma unroll
        for (int i = 0; i < 4; ++i) {
            shortx8 v = *(const shortx8*)(qg + (size_t)(i * 32 + row) * 2304 + c8);
            *(shortx8*)(qsh + (i * 32 + row) * 72 + c8) = v;
        }
    }
    __syncthreads();

    const int fr = lane & 15, fk = (lane >> 4) * 8;
    floatx4 acc[2][5] = {};
#pragma unroll
    for (int kc = 0; kc < 2; ++kc) {
        bf16x8 a[2], b[5];
#pragma unroll
        for (int rt = 0; rt < 2; ++rt)
            a[rt] = *(const bf16x8*)(qsh + (w * 32 + rt * 16 + fr) * 72 + kc * 32 + fk);
#pragma unroll
        for (int nt = 0; nt < 5; ++nt)
            b[nt] = *(const bf16x8*)(kvT + (nt * 16 + fr) * 72 + kc * 32 + fk);
#pragma unroll
        for (int rt = 0; rt < 2; ++rt)
#pragma unroll
            for (int nt = 0; nt < 5; ++nt)
                acc[rt][nt] = mfma_bf16(a[rt], b[nt], acc[rt][nt]);
    }
    if (fr == 0) {
#pragma unroll
        for (int rt = 0; rt < 2; ++rt)
#pragma unroll
            for (int r = 0; r < 4; ++r)
                dnm[w * 32 + rt * 16 + (lane >> 4) * 4 + r] = acc[rt][4][r];
    }
    __syncthreads();
#pragma unroll
    for (int rt = 0; rt < 2; ++rt) {
#pragma unroll
        for (int r = 0; r < 4; ++r) {
            int ml = w * 32 + rt * 16 + (lane >> 4) * 4 + r;
            float z = 1.f / dnm[ml];
            size_t base = (size_t)(bb * 4096 + l0 + ml) * 768 + head * 64;
#pragma unroll
            for (int nt = 0; nt < 4; ++nt)
                normed[base + nt * 16 + fr] = f2b(acc[rt][nt][r] * z);
        }
    }
}

// ---------------- launch ----------------
// Workspace (<=112,180,224 B, unchanged footprint):
//   kvp (12,779,520 B of f32 partials) ALIASES the Xb slot: Xb is dead between
//   k_gemm<0> (last reader) and k_num (writer of normed); k_kv writes kvp after
//   gemm<0>, k_kvred drains it into kvb before k_num overwrites the region.
//   Stream order serializes all of this — no race.
extern "C" void kernel_launch(void* const* d_in, const int* in_sizes, int n_in,
                              void* d_out, int out_size, void* d_ws, size_t ws_size,
                              hipStream_t stream) {
    const float* x  = (const float*)d_in[0];
    const float* Wq = (const float*)d_in[1];
    const float* bq = (const float*)d_in[2];
    const float* Wk = (const float*)d_in[3];
    const float* bk = (const float*)d_in[4];
    const float* Wv = (const float*)d_in[5];
    const float* bv = (const float*)d_in[6];
    const float* Wo = (const float*)d_in[7];
    const float* bo = (const float*)d_in[8];

    char* ws = (char*)d_ws;
    ushort* Xb   = (ushort*)(ws);                 // 25,165,824 B (reused: kvp, then normed)
    ushort* Wt   = (ushort*)(ws + 25165824);      //  3,538,944 B
    ushort* Wot  = (ushort*)(ws + 28704768);      //  1,179,648 B
    float*  bqkv = (float*)(ws + 29884416);       //      9,216 B
    ushort* QKV  = (ushort*)(ws + 29893632);      // 75,497,472 B
    ushort* kvb  = (ushort*)(ws + 111780864);     //    399,360 B
    float*  kvp  = (float*)(ws);                  // 12,779,520 B (aliases Xb; see above)
    ushort* normed = Xb;

    k_prep <<<dim3(6729),      256, 0, stream>>>(x, Xb, Wq, Wk, Wv, Wo, Wt, Wot,
                                                 bq, bk, bv, bqkv);
    k_gemm<0><<<dim3(128, 18), 256, 0, stream>>>(Xb, Wt, bqkv, (void*)QKV, 2304);
    k_kv   <<<dim3(48, 16),    256, 0, stream>>>(QKV, kvp);
    k_kvred<<<dim3(195),       256, 0, stream>>>(kvp, kvb);
    k_num  <<<dim3(48, 32),    256, 0, stream>>>(QKV, kvb, normed);
    k_gemm<1><<<dim3(128, 6),  256, 0, stream>>>(normed, Wot, bo, d_out, 768);
}